// Round 6
// baseline (60.729 us; speedup 1.0000x reference)
//
#include <hip/hip_runtime.h>

#define CC 512
#define CK 256
#define BB 8
#define TT 1024
#define NPROD 64
#define SSTR 32               // flag slots 128 B apart (kill L3 line contention)
#define MA 0x517E0001u
#define MB 0x517E0002u
#define MC 0x517E0003u

__device__ __forceinline__ float wave_allreduce(float v) {
#pragma unroll
    for (int m = 1; m < 64; m <<= 1) v += __shfl_xor(v, m, 64);
    return v;
}
__device__ __forceinline__ float dot4(float4 a, float4 b) {
    return a.x * b.x + a.y * b.y + a.z * b.z + a.w * b.w;
}
__device__ __forceinline__ void st_agent(float* p, float v) {
    __hip_atomic_store(p, v, __ATOMIC_RELAXED, __HIP_MEMORY_SCOPE_AGENT);
}
__device__ __forceinline__ float ld_agent(const float* p) {
    return __hip_atomic_load(p, __ATOMIC_RELAXED, __HIP_MEMORY_SCOPE_AGENT);
}
__device__ __forceinline__ void st_flag(unsigned* p, unsigned v) {
    __hip_atomic_store(p, v, __ATOMIC_RELAXED, __HIP_MEMORY_SCOPE_AGENT);
}
__device__ __forceinline__ unsigned ld_flag(const unsigned* p) {
    return __hip_atomic_load(p, __ATOMIC_RELAXED, __HIP_MEMORY_SCOPE_AGENT);
}

// D0: reset the 192 flag slots (runs BEFORE the fused kernel each call).
__global__ void __launch_bounds__(256)
reset_kernel(unsigned* __restrict__ slots) {
    if (threadIdx.x < 192) st_flag(&slots[threadIdx.x * SSTR], 0u);
}

// D1: fused producer/consumer.
//  blocks [0,64): chain  v1 = Wv@cond+bv -> v2 = W2@v1+b2 -> u = O@v2+ob
//                 (2 cols/wave, relaxed flag barriers, LDS staging)
//  all blocks:    prefetch x row + P row, poll done, w = P[c,:]@u[b,:]+pb[c],
//                 out[b,c,:] = x[b,c,:] + w
__global__ void __launch_bounds__(256)
fused_kernel(const float* __restrict__ x, const float* __restrict__ cond,
             const float* __restrict__ Wv, const float* __restrict__ bv,
             const float* __restrict__ W2, const float* __restrict__ b2,
             const float* __restrict__ O,  const float* __restrict__ ob,
             const float* __restrict__ P,  const float* __restrict__ pb,
             float* __restrict__ v1g, float* __restrict__ v2g,
             float* __restrict__ ug, unsigned* __restrict__ slots,
             float* __restrict__ out)
{
    __shared__ float lds[BB * CC];               // 16 KB (producers only)
    const int tid = threadIdx.x, lane = tid & 63, wvid = tid >> 6;
    const int row = blockIdx.x * 4 + wvid;       // 0..4095
    const int rb = row >> 9, rc = row & 511;

    if (blockIdx.x < NPROD) {
        const int c0 = (blockIdx.x * 4 + wvid) * 2;   // 2 columns per wave
        // ---- P1: v1[b,c] = Wv[c,:]@cond[b,:] + bv[c]
        {
            const float4 wva = *(const float4*)&Wv[(size_t)c0 * CK + lane * 4];
            const float4 wvb = *(const float4*)&Wv[(size_t)(c0 + 1) * CK + lane * 4];
            const float bva = bv[c0], bvb = bv[c0 + 1];
            float a0[BB], a1[BB];
#pragma unroll
            for (int b = 0; b < BB; ++b) {
                const float4 cd = *(const float4*)&cond[b * CK + lane * 4];
                a0[b] = dot4(wva, cd);
                a1[b] = dot4(wvb, cd);
            }
#pragma unroll
            for (int b = 0; b < BB; ++b) {
                const float r0 = wave_allreduce(a0[b]);
                const float r1 = wave_allreduce(a1[b]);
                if (lane == 0) {
                    st_agent(&v1g[b * CC + c0], r0 + bva);
                    st_agent(&v1g[b * CC + c0 + 1], r1 + bvb);
                }
            }
        }
        __syncthreads();
        if (tid == 0) {
            asm volatile("s_waitcnt vmcnt(0)" ::: "memory");
            st_flag(&slots[blockIdx.x * SSTR], MA);
        }
        // prefetch W2 rows while others arrive
        const float4 w2a0 = *(const float4*)&W2[(size_t)c0 * CC + lane * 4];
        const float4 w2a1 = *(const float4*)&W2[(size_t)c0 * CC + CK + lane * 4];
        const float4 w2b0 = *(const float4*)&W2[(size_t)(c0 + 1) * CC + lane * 4];
        const float4 w2b1 = *(const float4*)&W2[(size_t)(c0 + 1) * CC + CK + lane * 4];
        const float b2a = b2[c0], b2b = b2[c0 + 1];
        __builtin_amdgcn_sched_barrier(0);
        {
            const unsigned* sp = &slots[(tid & 63) * SSTR];
            while (ld_flag(sp) != MA) __builtin_amdgcn_s_sleep(1);
        }
        asm volatile("" ::: "memory");
        __syncthreads();
#pragma unroll
        for (int i = 0; i < 16; ++i)
            lds[tid + i * 256] = ld_agent(&v1g[tid + i * 256]);
        __syncthreads();
        // ---- P2: v2[b,c] = W2[c,:]@v1[b,:] + b2[c]
        {
            float a0[BB], a1[BB];
#pragma unroll
            for (int b = 0; b < BB; ++b) {
                const float4 va = *(const float4*)&lds[b * CC + lane * 4];
                const float4 vb = *(const float4*)&lds[b * CC + CK + lane * 4];
                a0[b] = dot4(w2a0, va) + dot4(w2a1, vb);
                a1[b] = dot4(w2b0, va) + dot4(w2b1, vb);
            }
#pragma unroll
            for (int b = 0; b < BB; ++b) {
                const float r0 = wave_allreduce(a0[b]);
                const float r1 = wave_allreduce(a1[b]);
                if (lane == 0) {
                    st_agent(&v2g[b * CC + c0], r0 + b2a);
                    st_agent(&v2g[b * CC + c0 + 1], r1 + b2b);
                }
            }
        }
        __syncthreads();
        if (tid == 0) {
            asm volatile("s_waitcnt vmcnt(0)" ::: "memory");
            st_flag(&slots[(64 + blockIdx.x) * SSTR], MB);
        }
        const float4 oa0 = *(const float4*)&O[(size_t)c0 * CC + lane * 4];
        const float4 oa1 = *(const float4*)&O[(size_t)c0 * CC + CK + lane * 4];
        const float4 ob0 = *(const float4*)&O[(size_t)(c0 + 1) * CC + lane * 4];
        const float4 ob1 = *(const float4*)&O[(size_t)(c0 + 1) * CC + CK + lane * 4];
        const float oba = ob[c0], obb = ob[c0 + 1];
        __builtin_amdgcn_sched_barrier(0);
        {
            const unsigned* sp = &slots[(64 + (tid & 63)) * SSTR];
            while (ld_flag(sp) != MB) __builtin_amdgcn_s_sleep(1);
        }
        asm volatile("" ::: "memory");
        __syncthreads();
#pragma unroll
        for (int i = 0; i < 16; ++i)
            lds[tid + i * 256] = ld_agent(&v2g[tid + i * 256]);
        __syncthreads();
        // ---- P3: u[b,c] = O[c,:]@v2[b,:] + ob[c]
        {
            float a0[BB], a1[BB];
#pragma unroll
            for (int b = 0; b < BB; ++b) {
                const float4 va = *(const float4*)&lds[b * CC + lane * 4];
                const float4 vb = *(const float4*)&lds[b * CC + CK + lane * 4];
                a0[b] = dot4(oa0, va) + dot4(oa1, vb);
                a1[b] = dot4(ob0, va) + dot4(ob1, vb);
            }
#pragma unroll
            for (int b = 0; b < BB; ++b) {
                const float r0 = wave_allreduce(a0[b]);
                const float r1 = wave_allreduce(a1[b]);
                if (lane == 0) {
                    st_agent(&ug[b * CC + c0], r0 + oba);
                    st_agent(&ug[b * CC + c0 + 1], r1 + obb);
                }
            }
        }
        __syncthreads();
        if (tid == 0) {
            asm volatile("s_waitcnt vmcnt(0)" ::: "memory");
            st_flag(&slots[(128 + blockIdx.x) * SSTR], MC);
        }
    }

    // ---- consumer tail (ALL blocks): overlap x/P prefetch with the chain
    const float4* x4 = (const float4*)x + (size_t)row * (TT / 4);
    float4 xr[4];
#pragma unroll
    for (int i = 0; i < 4; ++i) xr[i] = x4[i * 64 + lane];
    float pr[8];
#pragma unroll
    for (int i = 0; i < 8; ++i) pr[i] = P[(size_t)rc * CC + i * 64 + lane];
    const float pbc = pb[rc];
    __builtin_amdgcn_sched_barrier(0);
    {
        const unsigned* sp = &slots[(128 + (tid & 63)) * SSTR];
        while (ld_flag(sp) != MC) __builtin_amdgcn_s_sleep(2);
    }
    asm volatile("" ::: "memory");
    float acc = 0.f;
#pragma unroll
    for (int i = 0; i < 8; ++i)
        acc += pr[i] * ld_agent(&ug[rb * CC + i * 64 + lane]);
    const float w = wave_allreduce(acc) + pbc;
    float4* o4 = (float4*)out + (size_t)row * (TT / 4);
#pragma unroll
    for (int i = 0; i < 4; ++i) {
        float4 v = xr[i];
        v.x += w; v.y += w; v.z += w; v.w += w;
        o4[i * 64 + lane] = v;
    }
}

extern "C" void kernel_launch(void* const* d_in, const int* in_sizes, int n_in,
                              void* d_out, int out_size, void* d_ws, size_t ws_size,
                              hipStream_t stream) {
    const float* x    = (const float*)d_in[0];
    const float* cond = (const float*)d_in[1];
    const float* Wv   = (const float*)d_in[8];
    const float* bv   = (const float*)d_in[9];
    const float* W2   = (const float*)d_in[10] + 2 * CC * CC;  // in_proj_w rows [2C,3C)
    const float* b2   = (const float*)d_in[11] + 2 * CC;
    const float* O    = (const float*)d_in[12];
    const float* ob   = (const float*)d_in[13];
    const float* P    = (const float*)d_in[14];
    const float* pb   = (const float*)d_in[15];
    float* out = (float*)d_out;

    float* v1g = (float*)d_ws;                    // 4096 f
    float* v2g = v1g + BB * CC;                   // 4096 f
    float* ug  = v2g + BB * CC;                   // 4096 f
    unsigned* slots = (unsigned*)(ug + BB * CC);  // 192 slots * 32 stride

    reset_kernel<<<1, 256, 0, stream>>>(slots);
    fused_kernel<<<1024, 256, 0, stream>>>(x, cond, Wv, bv, W2, b2, O, ob,
                                           P, pb, v1g, v2g, ug, slots, out);
}

// Round 8
// 48.968 us; speedup vs baseline: 1.2402x; 1.2402x over previous
//
#include <hip/hip_runtime.h>

#define CC 512
#define CK 256
#define BB 8
#define TT 1024

__device__ __forceinline__ float wave_allreduce(float v) {
#pragma unroll
    for (int m = 1; m < 64; m <<= 1) v += __shfl_xor(v, m, 64);
    return v;
}
__device__ __forceinline__ float dot4(float4 a, float4 b) {
    return a.x * b.x + a.y * b.y + a.z * b.z + a.w * b.w;
}

// D1: blocks [0,256): PO split-K partials. 64x64 tile, kc in [0,4) over K=128.
//     blocks [256,288): v1[b,c] = Wv[c,:]@cond[b,:] + bv[c]
//     blocks [288,296): t2[c]   = P[c,:]@out_b + proj_b[c]
__global__ void __launch_bounds__(256)
d1_kernel(const float* __restrict__ P, const float* __restrict__ O,
          const float* __restrict__ Wv, const float* __restrict__ bv,
          const float* __restrict__ ob, const float* __restrict__ pb,
          const float* __restrict__ cond,
          float* __restrict__ POpart, float* __restrict__ v1,
          float* __restrict__ t2)
{
    __shared__ float As[64][36];   // P tile rows x k (pad 4)
    __shared__ float Bs[32][68];   // O tile k x cols (pad 4)
    const int blk = blockIdx.x, tid = threadIdx.x;
    const int lane = tid & 63, wvid = tid >> 6;

    if (blk < 256) {
        const int kc = blk >> 6, t = blk & 63;
        const int ti = t >> 3, tj = t & 7;            // 8x8 tile grid
        const int ty = tid >> 4, tx = tid & 15;       // 16x16 threads, 4x4 each
        float acc[4][4] = {};
        const int ar = tid >> 3, ac4 = (tid & 7) * 4;   // A staging: 32 rows/pass
        const int br = tid >> 4, bc4 = (tid & 15) * 4;  // B staging: 16 rows/pass

        for (int ch = 0; ch < 4; ++ch) {
            const int kb = kc * 128 + ch * 32;
            // issue global loads for this chunk (regs), overlap with prior compute
            const float4 a0 = *(const float4*)&P[(size_t)(ti * 64 + ar) * CC + kb + ac4];
            const float4 a1 = *(const float4*)&P[(size_t)(ti * 64 + 32 + ar) * CC + kb + ac4];
            const float4 b0 = *(const float4*)&O[(size_t)(kb + br) * CC + tj * 64 + bc4];
            const float4 b1 = *(const float4*)&O[(size_t)(kb + 16 + br) * CC + tj * 64 + bc4];
            __syncthreads();          // prior chunk's consumers done
            *(float4*)&As[ar][ac4] = a0;
            *(float4*)&As[32 + ar][ac4] = a1;
            *(float4*)&Bs[br][bc4] = b0;
            *(float4*)&Bs[16 + br][bc4] = b1;
            __syncthreads();
#pragma unroll
            for (int kk = 0; kk < 32; ++kk) {
                const float a_0 = As[4 * ty + 0][kk];
                const float a_1 = As[4 * ty + 1][kk];
                const float a_2 = As[4 * ty + 2][kk];
                const float a_3 = As[4 * ty + 3][kk];
                const float4 bq = *(const float4*)&Bs[kk][4 * tx];
                acc[0][0] += a_0 * bq.x; acc[0][1] += a_0 * bq.y;
                acc[0][2] += a_0 * bq.z; acc[0][3] += a_0 * bq.w;
                acc[1][0] += a_1 * bq.x; acc[1][1] += a_1 * bq.y;
                acc[1][2] += a_1 * bq.z; acc[1][3] += a_1 * bq.w;
                acc[2][0] += a_2 * bq.x; acc[2][1] += a_2 * bq.y;
                acc[2][2] += a_2 * bq.z; acc[2][3] += a_2 * bq.w;
                acc[3][0] += a_3 * bq.x; acc[3][1] += a_3 * bq.y;
                acc[3][2] += a_3 * bq.z; acc[3][3] += a_3 * bq.w;
            }
        }
        float* dst = POpart + (size_t)kc * (CC * CC) +
                     (size_t)(ti * 64 + 4 * ty) * CC + tj * 64 + 4 * tx;
#pragma unroll
        for (int i = 0; i < 4; ++i) {
            float4 v = { acc[i][0], acc[i][1], acc[i][2], acc[i][3] };
            *(float4*)&dst[(size_t)i * CC] = v;
        }
    } else if (blk < 288) {
        // v1: K=256 GEMV. idx -> (b, quarter); wave does 32 rows.
        const int idx = blk - 256;
        const int b = idx >> 2, q = idx & 3;
        const float4 cd = *(const float4*)&cond[b * CK + lane * 4];
        for (int r = 0; r < 32; ++r) {
            const int c = q * 128 + wvid * 32 + r;
            const float4 wv = *(const float4*)&Wv[(size_t)c * CK + lane * 4];
            const float s = wave_allreduce(dot4(wv, cd));
            if (lane == 0) v1[b * CC + c] = s + bv[c];
        }
    } else {
        // t2: K=512 GEMV vs out_b. 8 blocks x 4 waves x 16 rows.
        const int idx = blk - 288;
        const float4 oba = *(const float4*)&ob[lane * 4];
        const float4 obb = *(const float4*)&ob[CK + lane * 4];
        for (int r = 0; r < 16; ++r) {
            const int c = idx * 64 + wvid * 16 + r;
            const float4 pa = *(const float4*)&P[(size_t)c * CC + lane * 4];
            const float4 pbq = *(const float4*)&P[(size_t)c * CC + CK + lane * 4];
            const float s = wave_allreduce(dot4(pa, oba) + dot4(pbq, obb));
            if (lane == 0) t2[c] = s + pb[c];
        }
    }
}

// D2: blocks [0,256): PO = sum of 4 partials, in place into part 0.
//     blocks [256,288): v2[b,c] = W2[c,:]@v1[b,:] + b2[c]
__global__ void __launch_bounds__(256)
d2_kernel(float* __restrict__ POpart, const float* __restrict__ W2,
          const float* __restrict__ b2, const float* __restrict__ v1,
          float* __restrict__ v2)
{
    const int blk = blockIdx.x, tid = threadIdx.x;
    const int lane = tid & 63, wvid = tid >> 6;
    if (blk < 256) {
        float4* p0 = (float4*)POpart;
        const size_t i = (size_t)blk * 256 + tid;       // 65536 float4 total
        const size_t s4 = (size_t)CC * CC / 4;          // part stride in float4
        float4 a = p0[i], bq = p0[i + s4], cq = p0[i + 2 * s4], d = p0[i + 3 * s4];
        a.x += bq.x + cq.x + d.x; a.y += bq.y + cq.y + d.y;
        a.z += bq.z + cq.z + d.z; a.w += bq.w + cq.w + d.w;
        p0[i] = a;
    } else {
        const int idx = blk - 256;
        const int b = idx >> 2, q = idx & 3;
        const float4 va = *(const float4*)&v1[b * CC + lane * 4];
        const float4 vb = *(const float4*)&v1[b * CC + CK + lane * 4];
        for (int r = 0; r < 32; ++r) {
            const int c = q * 128 + wvid * 32 + r;
            const float4 wa = *(const float4*)&W2[(size_t)c * CC + lane * 4];
            const float4 wb = *(const float4*)&W2[(size_t)c * CC + CK + lane * 4];
            const float s = wave_allreduce(dot4(wa, va) + dot4(wb, vb));
            if (lane == 0) v2[b * CC + c] = s + b2[c];
        }
    }
}

// D3: wave per (b,c) row: w = PO[c,:]@v2[b,:] + t2[c]; out row = x row + w.
__global__ void __launch_bounds__(256)
stream_kernel(const float* __restrict__ x, const float* __restrict__ PO,
              const float* __restrict__ t2, const float* __restrict__ v2,
              float* __restrict__ out)
{
    const int tid = threadIdx.x, lane = tid & 63;
    const int row = blockIdx.x * 4 + (tid >> 6);   // 0..4095
    const int b = row >> 9, c = row & 511;

    const float4 pa = *(const float4*)&PO[(size_t)c * CC + lane * 4];
    const float4 pc = *(const float4*)&PO[(size_t)c * CC + CK + lane * 4];
    const float4 ua = *(const float4*)&v2[b * CC + lane * 4];
    const float4 ub = *(const float4*)&v2[b * CC + CK + lane * 4];
    const float w = wave_allreduce(dot4(pa, ua) + dot4(pc, ub)) + t2[c];

    const float4* x4 = (const float4*)x + (size_t)row * (TT / 4);
    float4* o4 = (float4*)out + (size_t)row * (TT / 4);
#pragma unroll
    for (int i = 0; i < 4; ++i) {
        float4 v = x4[i * 64 + lane];
        v.x += w; v.y += w; v.z += w; v.w += w;
        o4[i * 64 + lane] = v;
    }
}

extern "C" void kernel_launch(void* const* d_in, const int* in_sizes, int n_in,
                              void* d_out, int out_size, void* d_ws, size_t ws_size,
                              hipStream_t stream) {
    const float* x    = (const float*)d_in[0];
    const float* cond = (const float*)d_in[1];
    const float* Wv   = (const float*)d_in[8];
    const float* bv   = (const float*)d_in[9];
    const float* W2   = (const float*)d_in[10] + 2 * CC * CC;  // in_proj_w rows [2C,3C)
    const float* b2   = (const float*)d_in[11] + 2 * CC;
    const float* O    = (const float*)d_in[12];
    const float* ob   = (const float*)d_in[13];
    const float* P    = (const float*)d_in[14];
    const float* pb   = (const float*)d_in[15];
    float* out = (float*)d_out;

    float* POpart = (float*)d_ws;                  // 4 x 512x512 f = 4 MB; part0 -> PO
    float* v1 = POpart + 4 * CC * CC;              // 4096 f
    float* v2 = v1 + BB * CC;                      // 4096 f
    float* t2 = v2 + BB * CC;                      // 512 f

    d1_kernel<<<296, 256, 0, stream>>>(P, O, Wv, bv, ob, pb, cond, POpart, v1, t2);
    d2_kernel<<<288, 256, 0, stream>>>(POpart, W2, b2, v1, v2);
    stream_kernel<<<1024, 256, 0, stream>>>(x, POpart, t2, v2, out);
}

// Round 9
// 22.950 us; speedup vs baseline: 2.6462x; 2.1337x over previous
//
#include <hip/hip_runtime.h>

#define CC 512
#define CK 256
#define BB 8
#define TT 1024
#define POSTRIDE (CC * CC)          // one split-K partial, in floats

__device__ __forceinline__ float wave_allreduce(float v) {
#pragma unroll
    for (int m = 1; m < 64; m <<= 1) v += __shfl_xor(v, m, 64);
    return v;
}
__device__ __forceinline__ float dot4(float4 a, float4 b) {
    return a.x * b.x + a.y * b.y + a.z * b.z + a.w * b.w;
}

// D1: blocks [0,256):     POpart[kc] = P[:, kc*128:+128] @ O[kc*128:+128, :]
//     blocks [256,1280):  v1[b,c] = Wv[c,:]@cond[b,:] + bv[c]   (1 row/wave)
//     blocks [1280,1408): t2[c]   = P[c,:]@out_b + proj_b[c]    (1 row/wave)
__global__ void __launch_bounds__(256)
d1_kernel(const float* __restrict__ P, const float* __restrict__ O,
          const float* __restrict__ Wv, const float* __restrict__ bv,
          const float* __restrict__ ob, const float* __restrict__ pb,
          const float* __restrict__ cond,
          float* __restrict__ POpart, float* __restrict__ v1,
          float* __restrict__ t2)
{
    const int blk = blockIdx.x, tid = threadIdx.x;
    const int lane = tid & 63, wvid = tid >> 6;

    if (blk < 256) {
        __shared__ float As[64][36];   // 9.2 KB
        __shared__ float Bs[32][68];   // 8.7 KB
        const int kc = blk >> 6, t = blk & 63;
        const int ti = t >> 3, tj = t & 7;            // 8x8 tile grid, 64x64 tiles
        const int ty = tid >> 4, tx = tid & 15;       // 16x16 threads, 4x4 outputs
        const int ar = tid >> 3, ac4 = (tid & 7) * 4; // A staging coords
        const int br = tid >> 4, bc4 = (tid & 15) * 4;// B staging coords
        float acc[4][4] = {};

        // preload chunk 0 into registers
        int kb = kc * 128;
        float4 a0 = *(const float4*)&P[(size_t)(ti * 64 + ar) * CC + kb + ac4];
        float4 a1 = *(const float4*)&P[(size_t)(ti * 64 + 32 + ar) * CC + kb + ac4];
        float4 b0 = *(const float4*)&O[(size_t)(kb + br) * CC + tj * 64 + bc4];
        float4 b1 = *(const float4*)&O[(size_t)(kb + 16 + br) * CC + tj * 64 + bc4];

        for (int ch = 0; ch < 4; ++ch) {
            __syncthreads();           // prior chunk's consumers done
            *(float4*)&As[ar][ac4] = a0;
            *(float4*)&As[32 + ar][ac4] = a1;
            *(float4*)&Bs[br][bc4] = b0;
            *(float4*)&Bs[16 + br][bc4] = b1;
            __syncthreads();
            if (ch < 3) {              // prefetch next chunk under compute
                kb = kc * 128 + (ch + 1) * 32;
                a0 = *(const float4*)&P[(size_t)(ti * 64 + ar) * CC + kb + ac4];
                a1 = *(const float4*)&P[(size_t)(ti * 64 + 32 + ar) * CC + kb + ac4];
                b0 = *(const float4*)&O[(size_t)(kb + br) * CC + tj * 64 + bc4];
                b1 = *(const float4*)&O[(size_t)(kb + 16 + br) * CC + tj * 64 + bc4];
            }
#pragma unroll
            for (int kk = 0; kk < 32; ++kk) {
                const float a_0 = As[4 * ty + 0][kk];
                const float a_1 = As[4 * ty + 1][kk];
                const float a_2 = As[4 * ty + 2][kk];
                const float a_3 = As[4 * ty + 3][kk];
                const float4 bq = *(const float4*)&Bs[kk][4 * tx];
                acc[0][0] += a_0 * bq.x; acc[0][1] += a_0 * bq.y;
                acc[0][2] += a_0 * bq.z; acc[0][3] += a_0 * bq.w;
                acc[1][0] += a_1 * bq.x; acc[1][1] += a_1 * bq.y;
                acc[1][2] += a_1 * bq.z; acc[1][3] += a_1 * bq.w;
                acc[2][0] += a_2 * bq.x; acc[2][1] += a_2 * bq.y;
                acc[2][2] += a_2 * bq.z; acc[2][3] += a_2 * bq.w;
                acc[3][0] += a_3 * bq.x; acc[3][1] += a_3 * bq.y;
                acc[3][2] += a_3 * bq.z; acc[3][3] += a_3 * bq.w;
            }
        }
        float* dst = POpart + (size_t)kc * POSTRIDE +
                     (size_t)(ti * 64 + 4 * ty) * CC + tj * 64 + 4 * tx;
#pragma unroll
        for (int i = 0; i < 4; ++i) {
            float4 v = { acc[i][0], acc[i][1], acc[i][2], acc[i][3] };
            *(float4*)&dst[(size_t)i * CC] = v;
        }
    } else if (blk < 1280) {
        // v1: one row per wave, all loads in flight (K=256 -> 1 float4/lane each)
        const int row = (blk - 256) * 4 + wvid;        // 0..4095
        const int b = row >> 9, c = row & 511;
        const float4 wv = *(const float4*)&Wv[(size_t)c * CK + lane * 4];
        const float4 cd = *(const float4*)&cond[b * CK + lane * 4];
        const float s = wave_allreduce(dot4(wv, cd));
        if (lane == 0) v1[row] = s + bv[c];
    } else {
        // t2: one row per wave (K=512 -> 2 float4/lane each)
        const int c = (blk - 1280) * 4 + wvid;         // 0..511
        const float4 pa = *(const float4*)&P[(size_t)c * CC + lane * 4];
        const float4 pc = *(const float4*)&P[(size_t)c * CC + CK + lane * 4];
        const float4 oa = *(const float4*)&ob[lane * 4];
        const float4 oc = *(const float4*)&ob[CK + lane * 4];
        const float s = wave_allreduce(dot4(pa, oa) + dot4(pc, oc));
        if (lane == 0) t2[c] = s + pb[c];
    }
}

// D2: v2[b,c] = W2[c,:]@v1[b,:] + b2[c] — one row per wave, 1024 blocks.
__global__ void __launch_bounds__(256)
d2_kernel(const float* __restrict__ W2, const float* __restrict__ b2,
          const float* __restrict__ v1, float* __restrict__ v2)
{
    const int tid = threadIdx.x, lane = tid & 63;
    const int row = blockIdx.x * 4 + (tid >> 6);       // 0..4095
    const int b = row >> 9, c = row & 511;
    const float4 wa = *(const float4*)&W2[(size_t)c * CC + lane * 4];
    const float4 wb = *(const float4*)&W2[(size_t)c * CC + CK + lane * 4];
    const float4 va = *(const float4*)&v1[b * CC + lane * 4];
    const float4 vb = *(const float4*)&v1[b * CC + CK + lane * 4];
    const float s = wave_allreduce(dot4(wa, va) + dot4(wb, vb));
    if (lane == 0) v2[row] = s + b2[c];
}

// D3: wave per (b,c) row: w = sum_p POpart[p][c,:]@v2[b,:] + t2[c];
//     out[b,c,:] = x[b,c,:] + w.  x loads issued first (HBM-bound part).
__global__ void __launch_bounds__(256)
stream_kernel(const float* __restrict__ x, const float* __restrict__ POpart,
              const float* __restrict__ t2, const float* __restrict__ v2,
              float* __restrict__ out)
{
    const int tid = threadIdx.x, lane = tid & 63;
    const int row = blockIdx.x * 4 + (tid >> 6);       // 0..4095
    const int b = row >> 9, c = row & 511;

    const float4* x4 = (const float4*)x + (size_t)row * (TT / 4);
    float4 xr[4];
#pragma unroll
    for (int i = 0; i < 4; ++i) xr[i] = x4[i * 64 + lane];

    const float4 ua = *(const float4*)&v2[b * CC + lane * 4];
    const float4 ub = *(const float4*)&v2[b * CC + CK + lane * 4];
    float acc = 0.f;
#pragma unroll
    for (int p = 0; p < 4; ++p) {
        const float* prow = POpart + (size_t)p * POSTRIDE + (size_t)c * CC;
        const float4 pa = *(const float4*)&prow[lane * 4];
        const float4 pc = *(const float4*)&prow[CK + lane * 4];
        acc += dot4(pa, ua) + dot4(pc, ub);
    }
    const float w = wave_allreduce(acc) + t2[c];

    float4* o4 = (float4*)out + (size_t)row * (TT / 4);
#pragma unroll
    for (int i = 0; i < 4; ++i) {
        float4 v = xr[i];
        v.x += w; v.y += w; v.z += w; v.w += w;
        o4[i * 64 + lane] = v;
    }
}

extern "C" void kernel_launch(void* const* d_in, const int* in_sizes, int n_in,
                              void* d_out, int out_size, void* d_ws, size_t ws_size,
                              hipStream_t stream) {
    const float* x    = (const float*)d_in[0];
    const float* cond = (const float*)d_in[1];
    const float* Wv   = (const float*)d_in[8];
    const float* bv   = (const float*)d_in[9];
    const float* W2   = (const float*)d_in[10] + 2 * CC * CC;  // in_proj_w rows [2C,3C)
    const float* b2   = (const float*)d_in[11] + 2 * CC;
    const float* O    = (const float*)d_in[12];
    const float* ob   = (const float*)d_in[13];
    const float* P    = (const float*)d_in[14];
    const float* pb   = (const float*)d_in[15];
    float* out = (float*)d_out;

    float* POpart = (float*)d_ws;                  // 4 MB (4 partials)
    float* v1 = POpart + 4 * POSTRIDE;             // 4096 f
    float* v2 = v1 + BB * CC;                      // 4096 f
    float* t2 = v2 + BB * CC;                      // 512 f

    d1_kernel<<<1408, 256, 0, stream>>>(P, O, Wv, bv, ob, pb, cond, POpart, v1, t2);
    d2_kernel<<<1024, 256, 0, stream>>>(W2, b2, v1, v2);
    stream_kernel<<<1024, 256, 0, stream>>>(x, POpart, t2, v2, out);
}